// Round 11
// baseline (207.765 us; speedup 1.0000x reference)
//
#include <hip/hip_runtime.h>

// Problem constants
#define B_     16
#define C_     256
#define H_     32
#define W_     32
#define O_     256
#define K2_    9
#define HW_    1024
#define KTOT   2304     // 256*9
#define NPOS   16384    // B*H*W
#define NCHUNK 288      // KTOT/8 16B-chunks

typedef __bf16 bf16;
typedef __attribute__((ext_vector_type(8))) __bf16 bf16x8;
typedef __attribute__((ext_vector_type(4))) float  f32x4;

__device__ __forceinline__ void gload_lds16(const bf16* g, bf16* l) {
    __builtin_amdgcn_global_load_lds(
        (const __attribute__((address_space(1))) void*)g,
        (__attribute__((address_space(3))) void*)l, 16, 0, 0);
}

__device__ __forceinline__ float4 load4(const float* p, int t) {
    return ((const float4*)p)[t];
}
__device__ __forceinline__ float4 load4(const bf16* p, int t) {
    const ushort4 u = ((const ushort4*)p)[t];
    float4 f;
    f.x = __uint_as_float((unsigned)u.x << 16);
    f.y = __uint_as_float((unsigned)u.y << 16);
    f.z = __uint_as_float((unsigned)u.z << 16);
    f.w = __uint_as_float((unsigned)u.w << 16);
    return f;
}

// ---------------------------------------------------------------------------
// prep_w: BOTH layers in one launch (512 blocks: bx<256 -> layer1, else 2).
// w [O][C][3][3] f32 -> Wt[om][chunk][o128][8] bf16; chunk = cg*9+tap,
// c = cg*8+cl. Blocks 0..15 also zero pooled[16][256] (runs before gemm).
// ---------------------------------------------------------------------------
__global__ __launch_bounds__(256) void prep_w(
    const float* __restrict__ w1, const float* __restrict__ w2,
    bf16* __restrict__ Wt1, bf16* __restrict__ Wt2,
    float* __restrict__ pooled)
{
    const int bx = blockIdx.x;
    const float* w  = (bx < 256) ? w1 : w2;
    bf16*      Wt   = (bx < 256) ? Wt1 : Wt2;
    const int o     = bx & 255;
    const int om    = o >> 7, o128 = o & 127;
    if (bx < 16) pooled[bx * 256 + threadIdx.x] = 0.f;
    for (int k = threadIdx.x; k < KTOT; k += 256) {
        const int cg  = k / 72;
        const int rem = k - cg * 72;
        const int tap = rem >> 3;
        const int cl  = rem & 7;
        const int c   = cg * 8 + cl;
        const int chunk = cg * 9 + tap;
        Wt[(((size_t)om * NCHUNK + chunk) * 128 + o128) * 8 + cl] =
            (bf16)w[((size_t)o * C_ + c) * K2_ + tap];
    }
}

// ---------------------------------------------------------------------------
// sample_kernel: build S2[t][chunk][p][8] bf16 (im2col, bilinear deform).
// Grid 2048: bx -> cg (8-chan group, 32), rq (4 rt-tiles, 4), b (16).
// Thread t owns (rt = rq*4 + t>>6, pos = t&63) x ALL 9 taps: perfectly
// balanced (9 items/thread), 18 offset loads issued upfront (ILP), 8
// ds_read_b128 gather + one coalesced 16B store per tap.
// ---------------------------------------------------------------------------
template<typename T>
__global__ __launch_bounds__(256, 4) void sample_kernel(
    const T* __restrict__ src, size_t c_stride, size_t b_stride,
    const float* __restrict__ off,
    bf16* __restrict__ S)
{
    __shared__ float4 xs4[2][1152];   // pixel-major planes, padded

    const int tid = threadIdx.x;
    const int cg  = blockIdx.x & 31;
    const int rq  = (blockIdx.x >> 5) & 3;
    const int b   = blockIdx.x >> 7;

    // ---- stage 8 planes pixel-major (register 4x4 transpose), once ----
    #pragma unroll
    for (int h = 0; h < 2; ++h) {
        const T* base = src + b * b_stride + (size_t)(cg * 8 + h * 4) * c_stride;
        const float4 v0 = load4(base,                tid);
        const float4 v1 = load4(base + c_stride,     tid);
        const float4 v2 = load4(base + 2 * c_stride, tid);
        const float4 v3 = load4(base + 3 * c_stride, tid);
        const int p0 = 4 * tid;
        xs4[h][(p0    ) + ((p0    ) >> 3)] = make_float4(v0.x, v1.x, v2.x, v3.x);
        xs4[h][(p0 + 1) + ((p0 + 1) >> 3)] = make_float4(v0.y, v1.y, v2.y, v3.y);
        xs4[h][(p0 + 2) + ((p0 + 2) >> 3)] = make_float4(v0.z, v1.z, v2.z, v3.z);
        xs4[h][(p0 + 3) + ((p0 + 3) >> 3)] = make_float4(v0.w, v1.w, v2.w, v3.w);
    }

    // ---- offsets for this thread's (y,x): all 9 taps upfront ----
    const int pos = tid & 63;
    const int rt  = rq * 4 + (tid >> 6);
    const int y   = rt * 2 + (pos >> 5);
    const int x   = pos & 31;
    const float* offb = off + ((size_t)(b * 18) << 10) + (y << 5) + x;
    float dyo[9], dxo[9];
    #pragma unroll
    for (int k = 0; k < 9; ++k) {
        dyo[k] = offb[(size_t)(2 * k) << 10];
        dxo[k] = offb[((size_t)(2 * k) << 10) + 1024];
    }
    __syncthreads();

    // ---- 9 taps: metadata in regs, gather, coalesced store ----
    const size_t tbase = ((size_t)(b * 16 + rt) * NCHUNK + cg * 9) * 64 * 8;
    #pragma unroll
    for (int tap = 0; tap < 9; ++tap) {
        const float yy = dyo[tap] + (float)(tap / 3 - 1) + (float)y;
        const float xx = dxo[tap] + (float)(tap % 3 - 1) + (float)x;
        const float fy0 = floorf(yy), fx0 = floorf(xx);
        const float dy = yy - fy0, dx = xx - fx0;
        const int iy0 = (int)fy0, ix0 = (int)fx0;
        const int iy1 = iy0 + 1,  ix1 = ix0 + 1;
        const bool vy0 = (iy0 >= 0) && (iy0 < H_);
        const bool vy1 = (iy1 >= 0) && (iy1 < H_);
        const bool vx0 = (ix0 >= 0) && (ix0 < W_);
        const bool vx1 = (ix1 >= 0) && (ix1 < W_);
        const int cy0 = min(max(iy0, 0), H_ - 1), cy1 = min(max(iy1, 0), H_ - 1);
        const int cx0 = min(max(ix0, 0), W_ - 1), cx1 = min(max(ix1, 0), W_ - 1);
        const int p00 = cy0 * W_ + cx0, p01 = cy0 * W_ + cx1;
        const int p10 = cy1 * W_ + cx0, p11 = cy1 * W_ + cx1;
        const float w00 = (vy0 && vx0) ? (1.f - dy) * (1.f - dx) : 0.f;
        const float w01 = (vy0 && vx1) ? (1.f - dy) * dx         : 0.f;
        const float w10 = (vy1 && vx0) ? dy * (1.f - dx)         : 0.f;
        const float w11 = (vy1 && vx1) ? dy * dx                 : 0.f;
        const int s0 = p00 + (p00 >> 3);
        const int s1 = p01 + (p01 >> 3);
        const int s2 = p10 + (p10 >> 3);
        const int s3 = p11 + (p11 >> 3);
        bf16x8 v;
        #pragma unroll
        for (int h = 0; h < 2; ++h) {
            const float4 a = xs4[h][s0], bb = xs4[h][s1];
            const float4 c = xs4[h][s2], d  = xs4[h][s3];
            v[h * 4 + 0] = (bf16)(w00 * a.x + w01 * bb.x + w10 * c.x + w11 * d.x);
            v[h * 4 + 1] = (bf16)(w00 * a.y + w01 * bb.y + w10 * c.y + w11 * d.y);
            v[h * 4 + 2] = (bf16)(w00 * a.z + w01 * bb.z + w10 * c.z + w11 * d.z);
            v[h * 4 + 3] = (bf16)(w00 * a.w + w01 * bb.w + w10 * c.w + w11 * d.w);
        }
        *(bf16x8*)(S + tbase + (size_t)tap * 64 * 8 + pos * 8) = v;
    }
}

// ---------------------------------------------------------------------------
// gemm_kernel: C[o][pos] = Wt . S2 (tiled-linear layouts). BM=128, BN=64,
// BK=64; grid 512 = om(2) x pn(256); 4 waves; wave tile 64x32 = 4x2 frags.
// Explicit LDS DOUBLE-BUFFER, ONE barrier/iter: stage(buf^1, kt+1) issued
// BEFORE compute(buf) so the 6 global_load_lds hide under MFMA+ds_read;
// the compiler-emitted vmcnt(0) before s_barrier provides the drain.
// POOL=false: F[o][pos] = relu(C+bias) bf16;  POOL=true: fused avg-pool.
// ---------------------------------------------------------------------------
template<bool POOL>
__global__ __launch_bounds__(256) void gemm_kernel(
    const bf16* __restrict__ A,    // Wt [2][288][128][8]
    const bf16* __restrict__ Bm,   // S2 [256][288][64][8]
    const float* __restrict__ bias,
    bf16* __restrict__ F,          // !POOL
    float* __restrict__ pooled)    // POOL
{
    __shared__ bf16 Al[2][8192];   // [buf][ch8][o128][cl8]
    __shared__ bf16 Bl[2][4096];   // [buf][ch8][p64][cl8]

    const int tid  = threadIdx.x;
    const int om   = blockIdx.x >> 8;   // 0..1
    const int pn   = blockIdx.x & 255;  // 0..255
    const int wave = tid >> 6, lane = tid & 63;
    const int wr   = wave >> 1, wc = wave & 1;
    const int l15  = lane & 15, l4 = lane >> 4;

    const bf16* Abase = A  + (size_t)om * NCHUNK * 128 * 8;
    const bf16* Bbase = Bm + (size_t)pn * NCHUNK * 64 * 8;

    f32x4 acc[4][2];
    #pragma unroll
    for (int m = 0; m < 4; ++m)
        #pragma unroll
        for (int n = 0; n < 2; ++n) acc[m][n] = (f32x4)0.f;

    #define STAGE(buf, kt)                                                    \
        do {                                                                  \
            _Pragma("unroll")                                                 \
            for (int i = 0; i < 4; ++i)                                       \
                gload_lds16(Abase + (size_t)(kt) * 8192 + (i * 256 + tid) * 8,\
                            &Al[buf][(i * 256 + wave * 64) * 8]);             \
            _Pragma("unroll")                                                 \
            for (int i = 0; i < 2; ++i)                                       \
                gload_lds16(Bbase + (size_t)(kt) * 4096 + (i * 256 + tid) * 8,\
                            &Bl[buf][(i * 256 + wave * 64) * 8]);             \
        } while (0)

    STAGE(0, 0);
    __syncthreads();                       // drain prologue stage

    for (int kt = 0; kt < NCHUNK / 8; ++kt) {
        const int cur = kt & 1;
        if (kt < NCHUNK / 8 - 1) STAGE(cur ^ 1, kt + 1);

        #pragma unroll
        for (int ks = 0; ks < 2; ++ks) {
            const int cb = ks * 4 + l4;          // chunk within K-step
            bf16x8 af[4], bq[2];
            #pragma unroll
            for (int m = 0; m < 4; ++m) {
                const int R = wr * 64 + m * 16 + l15;
                af[m] = *(const bf16x8*)&Al[cur][(cb * 128 + R) * 8];
            }
            #pragma unroll
            for (int n = 0; n < 2; ++n) {
                const int R = wc * 32 + n * 16 + l15;
                bq[n] = *(const bf16x8*)&Bl[cur][(cb * 64 + R) * 8];
            }
            #pragma unroll
            for (int m = 0; m < 4; ++m)
                #pragma unroll
                for (int n = 0; n < 2; ++n)
                    acc[m][n] = __builtin_amdgcn_mfma_f32_16x16x32_bf16(
                        af[m], bq[n], acc[m][n], 0, 0, 0);
        }
        __syncthreads();   // all waves done with buf[cur]; next stage done
    }
    #undef STAGE

    const int obase = om * 128 + wr * 64;
    if (!POOL) {
        #pragma unroll
        for (int m = 0; m < 4; ++m)
            #pragma unroll
            for (int j = 0; j < 4; ++j) {
                const int o  = obase + m * 16 + l4 * 4 + j;
                const float bb = bias[o];
                #pragma unroll
                for (int n = 0; n < 2; ++n) {
                    const int col = pn * 64 + wc * 32 + n * 16 + l15;
                    F[(size_t)o * NPOS + col] =
                        (bf16)fmaxf(acc[m][n][j] + bb, 0.f);
                }
            }
    } else {
        const int b = pn >> 4;   // pn*64 / 1024
        #pragma unroll
        for (int m = 0; m < 4; ++m)
            #pragma unroll
            for (int j = 0; j < 4; ++j) {
                const int o  = obase + m * 16 + l4 * 4 + j;
                const float bb = bias[o];
                float s = fmaxf(acc[m][0][j] + bb, 0.f) +
                          fmaxf(acc[m][1][j] + bb, 0.f);
                s += __shfl_xor(s, 1);
                s += __shfl_xor(s, 2);
                s += __shfl_xor(s, 4);
                s += __shfl_xor(s, 8);
                if (l15 == 0)
                    atomicAdd(&pooled[b * 256 + o], s * (1.f / 1024.f));
            }
    }
}

// ---------------------------------------------------------------------------
// FC: out[b,n] = pooled[b,:] . fc_w[n,:] + fc_b[n]. 64 blocks = (b, quarter).
// ---------------------------------------------------------------------------
__global__ __launch_bounds__(256) void fc_kernel(
    const float* __restrict__ pooled, const float* __restrict__ fw,
    const float* __restrict__ fb, float* __restrict__ out)
{
    __shared__ float pl[C_];
    const int b = blockIdx.x >> 2;
    const int q = blockIdx.x & 3;
    const int t = threadIdx.x;
    pl[t] = pooled[b * C_ + t];
    __syncthreads();
    const int n = q * 250 + t;
    if (t < 250) {
        const float4* wr = (const float4*)(fw + (size_t)n * C_);
        float s = 0.f;
        #pragma unroll 8
        for (int j = 0; j < C_ / 4; ++j) {
            const float4 v = wr[j];
            s += v.x * pl[4 * j] + v.y * pl[4 * j + 1] +
                 v.z * pl[4 * j + 2] + v.w * pl[4 * j + 3];
        }
        out[b * 1000 + n] = s + fb[n];
    }
}

extern "C" void kernel_launch(void* const* d_in, const int* in_sizes, int n_in,
                              void* d_out, int out_size, void* d_ws, size_t ws_size,
                              hipStream_t stream)
{
    const float* x   = (const float*)d_in[0];
    const float* off = (const float*)d_in[1];
    const float* w1  = (const float*)d_in[2];
    const float* b1  = (const float*)d_in[3];
    const float* w2  = (const float*)d_in[4];
    const float* b2  = (const float*)d_in[5];
    const float* fcw = (const float*)d_in[6];
    const float* fcb = (const float*)d_in[7];
    float* outp = (float*)d_out;

    // workspace layout (all 16B aligned)
    bf16*  S      = (bf16*)d_ws;                       // [256][288][64][8] 75.5MB
    bf16*  F2     = S + (size_t)NPOS * KTOT;           // [256][NPOS]        8.4MB
    bf16*  Wt1    = F2 + (size_t)O_ * NPOS;            // [2][288][128][8]   1.2MB
    bf16*  Wt2    = Wt1 + (size_t)O_ * KTOT;           //                    1.2MB
    float* pooled = (float*)(Wt2 + (size_t)O_ * KTOT); // [16][256]          16KB

    prep_w<<<512, 256, 0, stream>>>(w1, w2, Wt1, Wt2, pooled);

    // layer 1: sample from x [b][c][hw] f32
    sample_kernel<float><<<2048, 256, 0, stream>>>(
        x, (size_t)HW_, (size_t)C_ * HW_, off, S);
    gemm_kernel<false><<<512, 256, 0, stream>>>(Wt1, S, b1, F2, nullptr);

    // layer 2: sample from F2 [c][b*1024+hw] bf16
    sample_kernel<bf16><<<2048, 256, 0, stream>>>(
        F2, (size_t)NPOS, (size_t)HW_, off, S);
    gemm_kernel<true><<<512, 256, 0, stream>>>(Wt2, S, b2, nullptr, pooled);

    fc_kernel<<<B_ * 4, 256, 0, stream>>>(pooled, fcw, fcb, outp);
}